// Round 3
// baseline (69.438 us; speedup 1.0000x reference)
//
#include <hip/hip_runtime.h>

// InfoNCE/contrastive MVN loss:
// loss = mean_i( LSE_j((p_i.g_j - 0.5|g_j|^2)/nv) - (p_i.g_i - 0.5|g_i|^2)/nv ) * 2nv
// B = 8192, D = 256, fp32 inputs, scalar fp32 output.
// Main kernel: bf16 MFMA GEMM (P pre-scaled by s=log2e/nv) fused with online
// base-2 LSE; accumulator initialized to -0.5*s*|g_j|^2 so MFMA output IS the
// base-2 logit (zero per-element VALU prep before exp2).

typedef short short8 __attribute__((ext_vector_type(8)));
typedef float f32x4 __attribute__((ext_vector_type(4)));

#define LN2F 0.6931471805599453f
#define LOG2EF 1.4426950408889634f
#define NB 8192
#define ND 256
#define NCHUNK 16   // column chunks; chunk = 512 cols = 8 tiles of 64

__device__ __forceinline__ unsigned short f2bf(float f) {
  unsigned u = __float_as_uint(f);
  u += 0x7FFFu + ((u >> 16) & 1u);   // round-to-nearest-even
  return (unsigned short)(u >> 16);
}

// ---- kernel 1: convert to bf16 (P pre-scaled) + exact fp32 row stats -----
__global__ __launch_bounds__(256) void vmse_prep(
    const float* __restrict__ pred, const float* __restrict__ gt,
    const float* __restrict__ sigma,
    unsigned short* __restrict__ Ah, unsigned short* __restrict__ Bh,
    float* __restrict__ diag, float* __restrict__ gnorm,
    float* __restrict__ ghs)
{
  const float nv = sigma[0] * sigma[0];
  const float s = LOG2EF / nv;
  const int row = blockIdx.x * 4 + (threadIdx.x >> 6);
  const int lane = threadIdx.x & 63;
  const float4 p = *(const float4*)(pred + row * ND + lane * 4);
  const float4 g = *(const float4*)(gt   + row * ND + lane * 4);
  ushort4 pa, ga;
  pa.x = f2bf(p.x * s); pa.y = f2bf(p.y * s);
  pa.z = f2bf(p.z * s); pa.w = f2bf(p.w * s);
  ga.x = f2bf(g.x); ga.y = f2bf(g.y); ga.z = f2bf(g.z); ga.w = f2bf(g.w);
  *(ushort4*)(Ah + row * ND + lane * 4) = pa;
  *(ushort4*)(Bh + row * ND + lane * 4) = ga;
  float dd = p.x * g.x + p.y * g.y + p.z * g.z + p.w * g.w;
  float gg = g.x * g.x + g.y * g.y + g.z * g.z + g.w * g.w;
  #pragma unroll
  for (int off = 1; off < 64; off <<= 1) {
    dd += __shfl_xor(dd, off);
    gg += __shfl_xor(gg, off);
  }
  if (lane == 0) {
    diag[row] = dd;
    gnorm[row] = gg;
    ghs[row] = 0.5f * s * gg;   // base-2 logit offset for column j
  }
}

// ---- kernel 2: fused GEMM + online base-2 LSE ----------------------------
// grid 512 = 32 row-blocks x 16 column chunks. 512 threads = 8 waves.
// Each wave owns 32 pred rows (2 n-subtiles of 16); P frags resident in VGPRs.
// G tiles (64 cols x 256 K, bf16) double-buffered in LDS, 16B-chunk XOR
// swizzle (kc ^= row&7) for bank-spread ds_read_b128.
// Swapped mfma(G,P): col=lane&15 -> pred idx, row=(lane>>4)*4+reg -> gt idx,
// so the row-LSE is lane-local; cross-lane merge = shfl_xor 16,32.
__global__ __launch_bounds__(512, 4) void vmse_main(
    const unsigned short* __restrict__ Ah, const unsigned short* __restrict__ Bh,
    const float* __restrict__ ghs, float* __restrict__ partial)
{
  __shared__ unsigned short lds[2][64 * ND];   // 2 x 32 KB
  const int tid = threadIdx.x;
  const int lane = tid & 63;
  const int wid = tid >> 6;
  const int rb = blockIdx.x & 31;     // row block (256 rows)
  const int ch = blockIdx.x >> 5;     // column chunk (512 cols)
  const int r15 = lane & 15;
  const int hi = lane >> 4;
  const int swz = (lane & 7) << 3;    // XOR mask in ushort units (bits 3-5)

  // P fragments (pre-scaled): B-operand layout: n = lane&15, k = hi*8 + e
  short8 pf[2][8];
  #pragma unroll
  for (int ns = 0; ns < 2; ++ns) {
    const unsigned short* prow =
        Ah + (size_t)((rb * 256) + (wid * 32) + (ns * 16) + r15) * ND + hi * 8;
    #pragma unroll
    for (int kk = 0; kk < 8; ++kk)
      pf[ns][kk] = *(const short8*)(prow + kk * 32);
  }

  const int j0 = ch * 512;

  float m2[2], l2[2];
  #pragma unroll
  for (int ns = 0; ns < 2; ++ns) { m2[ns] = -3.0e38f; l2[ns] = 0.0f; }

  short8 st[4];
  // prologue: stage tile 0 (reg-staged; write side applies the same swizzle)
  {
    const unsigned short* src0 = Bh + (size_t)j0 * ND;
    #pragma unroll
    for (int it = 0; it < 4; ++it)
      st[it] = *(const short8*)(src0 + (it * 512 + tid) * 8);
    #pragma unroll
    for (int it = 0; it < 4; ++it) {
      const int c = it * 512 + tid;
      const int r = c >> 5, kc = c & 31;
      *(short8*)(&lds[0][r * ND + ((kc ^ (r & 7)) * 8)]) = st[it];
    }
  }
  __syncthreads();

  for (int t = 0; t < 8; ++t) {
    const int buf = t & 1;
    if (t + 1 < 8) {   // T14: issue next tile's global loads before compute
      const unsigned short* src0 = Bh + (size_t)(j0 + (t + 1) * 64) * ND;
      #pragma unroll
      for (int it = 0; it < 4; ++it)
        st[it] = *(const short8*)(src0 + (it * 512 + tid) * 8);
    }

    const unsigned short* ldsb = &lds[buf][0];
    #pragma unroll
    for (int ms = 0; ms < 4; ++ms) {
      // base-2 offsets for gt rows j = j0 + t*64 + ms*16 + hi*4 + e
      const float4 g4 = *(const float4*)(ghs + j0 + t * 64 + ms * 16 + hi * 4);
      f32x4 acc[2];
      #pragma unroll
      for (int ns = 0; ns < 2; ++ns)
        acc[ns] = (f32x4){-g4.x, -g4.y, -g4.z, -g4.w};
      const int rowb = (ms * 16 + r15) * ND;
      #pragma unroll
      for (int kk = 0; kk < 8; ++kk) {
        const short8 gf =
            *(const short8*)(ldsb + rowb + (((kk * 32) + (hi * 8)) ^ swz));
        acc[0] = __builtin_amdgcn_mfma_f32_16x16x32_bf16(gf, pf[0][kk], acc[0], 0, 0, 0);
        acc[1] = __builtin_amdgcn_mfma_f32_16x16x32_bf16(gf, pf[1][kk], acc[1], 0, 0, 0);
      }
      #pragma unroll
      for (int ns = 0; ns < 2; ++ns) {
        // acc IS the base-2 logit z
        const float z0 = acc[ns][0], z1 = acc[ns][1];
        const float z2 = acc[ns][2], z3 = acc[ns][3];
        const float tmax = fmaxf(fmaxf(z0, z1), fmaxf(z2, z3));
        if (__any(tmax > m2[ns] + 8.0f)) {      // T13 defer-max, rarely taken
          const float nm = fmaxf(m2[ns], tmax);
          l2[ns] *= exp2f(m2[ns] - nm);
          m2[ns] = nm;
        }
        const float e0 = exp2f(z0 - m2[ns]);
        const float e1 = exp2f(z1 - m2[ns]);
        const float e2 = exp2f(z2 - m2[ns]);
        const float e3 = exp2f(z3 - m2[ns]);
        l2[ns] += (e0 + e1) + (e2 + e3);
      }
    }
    __syncthreads();                    // all waves done reading old buffer
    if (t + 1 < 8) {
      const int nb = buf ^ 1;
      #pragma unroll
      for (int it = 0; it < 4; ++it) {
        const int c = it * 512 + tid;
        const int r = c >> 5, kc = c & 31;
        *(short8*)(&lds[nb][r * ND + ((kc ^ (r & 7)) * 8)]) = st[it];
      }
    }
    __syncthreads();                    // staged tile visible to all
  }

  // combine lanes {i, i+16, i+32, i+48} (same pred row), write base-2 partial LSE
  #pragma unroll
  for (int ns = 0; ns < 2; ++ns) {
    float m = m2[ns], l = l2[ns];
    #pragma unroll
    for (int off = 16; off <= 32; off <<= 1) {
      const float om = __shfl_xor(m, off);
      const float ol = __shfl_xor(l, off);
      const float nm = fmaxf(m, om);
      l = l * exp2f(m - nm) + ol * exp2f(om - nm);
      m = nm;
    }
    if (hi == 0) {
      const int row = rb * 256 + wid * 32 + ns * 16 + r15;
      partial[row * NCHUNK + ch] = m + log2f(l);
    }
  }
}

// ---- kernel 3: per-row combine of chunk partials + diagonal --------------
__global__ __launch_bounds__(256) void vmse_combine(
    const float* __restrict__ partial, const float* __restrict__ diag,
    const float* __restrict__ gnorm, const float* __restrict__ sigma,
    float* __restrict__ bsum)
{
  const int r = blockIdx.x * 256 + threadIdx.x;
  const float nv = sigma[0] * sigma[0];
  float p[NCHUNK];
  float M = -3.0e38f;
  #pragma unroll
  for (int c = 0; c < NCHUNK; ++c) { p[c] = partial[r * NCHUNK + c]; M = fmaxf(M, p[c]); }
  float ssum = 0.f;
  #pragma unroll
  for (int c = 0; c < NCHUNK; ++c) ssum += exp2f(p[c] - M);
  const float lse2 = M + log2f(ssum);          // base-2 LSE of z*log2e
  const float zii = (diag[r] - 0.5f * gnorm[r]) / nv;
  float contrib = LN2F * lse2 - zii;           // lse_e - z_ii
  #pragma unroll
  for (int off = 1; off < 64; off <<= 1) contrib += __shfl_xor(contrib, off);
  __shared__ float wsum[4];
  if ((threadIdx.x & 63) == 0) wsum[threadIdx.x >> 6] = contrib;
  __syncthreads();
  if (threadIdx.x == 0)
    bsum[blockIdx.x] = (wsum[0] + wsum[1]) + (wsum[2] + wsum[3]);
}

// ---- kernel 4: deterministic finalize ------------------------------------
__global__ __launch_bounds__(64) void vmse_final(
    const float* __restrict__ bsum, const float* __restrict__ sigma,
    float* __restrict__ out)
{
  const int lane = threadIdx.x;
  float v = (lane < 32) ? bsum[lane] : 0.f;
  #pragma unroll
  for (int off = 1; off < 64; off <<= 1) v += __shfl_xor(v, off);
  if (lane == 0) {
    const float nv = sigma[0] * sigma[0];
    out[0] = v * (2.0f * nv / (float)NB);
  }
}

extern "C" void kernel_launch(void* const* d_in, const int* in_sizes, int n_in,
                              void* d_out, int out_size, void* d_ws, size_t ws_size,
                              hipStream_t stream)
{
  const float* pred  = (const float*)d_in[0];
  const float* gt    = (const float*)d_in[1];
  const float* sigma = (const float*)d_in[2];
  char* ws = (char*)d_ws;
  // ws layout: Ah 4MB | Bh 4MB | gnorm 32KB | diag 32KB | ghs 32KB | partial 512KB | bsum
  unsigned short* Ah = (unsigned short*)(ws);
  unsigned short* Bh = (unsigned short*)(ws + (4u << 20));
  float* gnorm   = (float*)(ws + (8u << 20));
  float* diag    = (float*)(ws + (8u << 20) + (32u << 10));
  float* ghs     = (float*)(ws + (8u << 20) + (64u << 10));
  float* partial = (float*)(ws + (8u << 20) + (96u << 10));
  float* bsum    = (float*)(ws + (8u << 20) + (608u << 10));

  vmse_prep<<<NB / 4, 256, 0, stream>>>(pred, gt, sigma, Ah, Bh, diag, gnorm, ghs);
  vmse_main<<<32 * NCHUNK, 512, 0, stream>>>(Ah, Bh, ghs, partial);
  vmse_combine<<<NB / 256, 256, 0, stream>>>(partial, diag, gnorm, sigma, bsum);
  vmse_final<<<1, 64, 0, stream>>>(bsum, sigma, (float*)d_out);
}

// Round 4
// 63.689 us; speedup vs baseline: 1.0903x; 1.0903x over previous
//
#include <hip/hip_runtime.h>

// InfoNCE/contrastive MVN loss:
// loss = mean_i( LSE_j((p_i.g_j - 0.5|g_j|^2)/nv) - (p_i.g_i - 0.5|g_i|^2)/nv ) * 2nv
// B = 8192, D = 256, fp32 inputs, scalar fp32 output.
// Main kernel: bf16 MFMA GEMM (P pre-scaled by s=log2e/nv) fused with online
// base-2 LSE. G tiles staged via global_load_lds (width 16, linear LDS dest,
// inverse-XOR-swizzled global source per rule 21); one barrier per tile.

typedef short short8 __attribute__((ext_vector_type(8)));
typedef float f32x4 __attribute__((ext_vector_type(4)));

#define LN2F 0.6931471805599453f
#define LOG2EF 1.4426950408889634f
#define NB 8192
#define ND 256
#define NCHUNK 16   // column chunks; chunk = 512 cols = 8 tiles of 64

__device__ __forceinline__ unsigned short f2bf(float f) {
  unsigned u = __float_as_uint(f);
  u += 0x7FFFu + ((u >> 16) & 1u);   // round-to-nearest-even
  return (unsigned short)(u >> 16);
}

// ---- kernel 1: convert to bf16 (P pre-scaled) + exact fp32 row stats -----
__global__ __launch_bounds__(256) void vmse_prep(
    const float* __restrict__ pred, const float* __restrict__ gt,
    const float* __restrict__ sigma,
    unsigned short* __restrict__ Ah, unsigned short* __restrict__ Bh,
    float* __restrict__ diag, float* __restrict__ gnorm,
    float* __restrict__ ghs)
{
  const float nv = sigma[0] * sigma[0];
  const float s = LOG2EF / nv;
  const int row = blockIdx.x * 4 + (threadIdx.x >> 6);
  const int lane = threadIdx.x & 63;
  const float4 p = *(const float4*)(pred + row * ND + lane * 4);
  const float4 g = *(const float4*)(gt   + row * ND + lane * 4);
  ushort4 pa, ga;
  pa.x = f2bf(p.x * s); pa.y = f2bf(p.y * s);
  pa.z = f2bf(p.z * s); pa.w = f2bf(p.w * s);
  ga.x = f2bf(g.x); ga.y = f2bf(g.y); ga.z = f2bf(g.z); ga.w = f2bf(g.w);
  *(ushort4*)(Ah + row * ND + lane * 4) = pa;
  *(ushort4*)(Bh + row * ND + lane * 4) = ga;
  float dd = p.x * g.x + p.y * g.y + p.z * g.z + p.w * g.w;
  float gg = g.x * g.x + g.y * g.y + g.z * g.z + g.w * g.w;
  #pragma unroll
  for (int off = 1; off < 64; off <<= 1) {
    dd += __shfl_xor(dd, off);
    gg += __shfl_xor(gg, off);
  }
  if (lane == 0) {
    diag[row] = dd;
    gnorm[row] = gg;
    ghs[row] = 0.5f * s * gg;   // base-2 logit offset for column j
  }
}

// ---- kernel 2: fused GEMM + online base-2 LSE ----------------------------
// grid 512 = 32 row-blocks x 16 column chunks. 512 threads = 8 waves.
// Each wave owns 32 pred rows (2 n-subtiles of 16); P frags resident in VGPRs.
// G tiles (64 rows x 256 K bf16 = 32KB) double-buffered in LDS.
// Staging: global_load_lds width=16; LDS dest linear (wave-uniform base +
// lane*16); swizzle achieved by inverse-permuting the per-lane GLOBAL source
// chunk: LDS chunk j of row r holds global chunk j^(r&7). Reads XOR the same
// mask. Swapped mfma(G,P): col=lane&15 -> pred idx, row -> gt idx, so the
// row-LSE is lane-local; cross-lane merge = shfl_xor 16,32.
__global__ __launch_bounds__(512, 4) void vmse_main(
    const unsigned short* __restrict__ Ah, const unsigned short* __restrict__ Bh,
    const float* __restrict__ ghs, float* __restrict__ partial)
{
  __shared__ unsigned short lds[2][64 * ND];   // 2 x 32 KB
  __shared__ float lds_ghs[512];               // chunk's logit offsets
  const int tid = threadIdx.x;
  const int lane = tid & 63;
  const int wid = tid >> 6;
  const int rb = blockIdx.x & 31;     // row block (256 rows)
  const int ch = blockIdx.x >> 5;     // column chunk (512 cols)
  const int r15 = lane & 15;
  const int hi = lane >> 4;

  const int j0 = ch * 512;

  // P fragments (pre-scaled): B-operand layout: n = lane&15, k = hi*8 + e
  short8 pf[2][8];
  #pragma unroll
  for (int ns = 0; ns < 2; ++ns) {
    const unsigned short* prow =
        Ah + (size_t)((rb * 256) + (wid * 32) + (ns * 16) + r15) * ND + hi * 8;
    #pragma unroll
    for (int kk = 0; kk < 8; ++kk)
      pf[ns][kk] = *(const short8*)(prow + kk * 32);
  }

  // ghs chunk -> LDS (no vmcnt pollution of the staging pipeline later)
  lds_ghs[tid] = ghs[j0 + tid];

  // stage one 64x256 tile: 32 x 1KB wave-instructions; wave w does groups
  // q = w*4+i, rows 2q,2q+1. lane l: row r = 2q + (l>>5),
  // global chunk cg = (l&31) ^ (r&7), LDS linear (base q*1KB + l*16).
  #define STAGE(buf, t)                                                      \
    {                                                                        \
      _Pragma("unroll")                                                      \
      for (int i = 0; i < 4; ++i) {                                          \
        const int qq = wid * 4 + i;                                          \
        const int r = 2 * qq + (lane >> 5);                                  \
        const int cg = (lane & 31) ^ (r & 7);                                \
        const unsigned short* src =                                          \
            Bh + (size_t)(j0 + (t) * 64 + r) * ND + cg * 8;                  \
        __builtin_amdgcn_global_load_lds(                                    \
            (const __attribute__((address_space(1))) unsigned int*)src,      \
            (__attribute__((address_space(3))) unsigned int*)                \
                &lds[buf][qq * 512],                                         \
            16, 0, 0);                                                       \
      }                                                                      \
    }

  float m2[2], l2[2];
  #pragma unroll
  for (int ns = 0; ns < 2; ++ns) { m2[ns] = -3.0e38f; l2[ns] = 0.0f; }

  STAGE(0, 0);
  __syncthreads();   // drains vmcnt(0): tile 0 + lds_ghs ready

  for (int t = 0; t < 8; ++t) {
    const int buf = t & 1;
    if (t + 1 < 8) STAGE(buf ^ 1, t + 1);   // prefetch next tile, stays in flight

    const unsigned short* ldsb = &lds[buf][0];
    #pragma unroll
    for (int ms = 0; ms < 4; ++ms) {
      // base-2 offsets for gt rows j = j0 + t*64 + ms*16 + hi*4 + e (LDS bcast)
      const float4 g4 = *(const float4*)(&lds_ghs[t * 64 + ms * 16 + hi * 4]);
      f32x4 acc[2];
      #pragma unroll
      for (int ns = 0; ns < 2; ++ns)
        acc[ns] = (f32x4){-g4.x, -g4.y, -g4.z, -g4.w};
      const int rowb = (ms * 16 + r15) * ND;
      #pragma unroll
      for (int kk = 0; kk < 8; ++kk) {
        // logical chunk c = kk*4+hi of row (ms*16+r15); physical c ^ (row&7)
        const short8 gf = *(const short8*)(
            ldsb + rowb + ((((kk * 4) + hi) ^ (r15 & 7)) * 8));
        acc[0] = __builtin_amdgcn_mfma_f32_16x16x32_bf16(gf, pf[0][kk], acc[0], 0, 0, 0);
        acc[1] = __builtin_amdgcn_mfma_f32_16x16x32_bf16(gf, pf[1][kk], acc[1], 0, 0, 0);
      }
      #pragma unroll
      for (int ns = 0; ns < 2; ++ns) {
        // acc IS the base-2 logit z
        const float z0 = acc[ns][0], z1 = acc[ns][1];
        const float z2 = acc[ns][2], z3 = acc[ns][3];
        const float tmax = fmaxf(fmaxf(z0, z1), fmaxf(z2, z3));
        if (__any(tmax > m2[ns] + 8.0f)) {      // T13 defer-max, rarely taken
          const float nm = fmaxf(m2[ns], tmax);
          l2[ns] *= exp2f(m2[ns] - nm);
          m2[ns] = nm;
        }
        const float e0 = exp2f(z0 - m2[ns]);
        const float e1 = exp2f(z1 - m2[ns]);
        const float e2 = exp2f(z2 - m2[ns]);
        const float e3 = exp2f(z3 - m2[ns]);
        l2[ns] += (e0 + e1) + (e2 + e3);
      }
    }
    __syncthreads();   // vmcnt(0)+barrier: prefetch landed, all waves done with buf
  }

  // combine lanes {i, i+16, i+32, i+48} (same pred row), write base-2 partial LSE
  #pragma unroll
  for (int ns = 0; ns < 2; ++ns) {
    float m = m2[ns], l = l2[ns];
    #pragma unroll
    for (int off = 16; off <= 32; off <<= 1) {
      const float om = __shfl_xor(m, off);
      const float ol = __shfl_xor(l, off);
      const float nm = fmaxf(m, om);
      l = l * exp2f(m - nm) + ol * exp2f(om - nm);
      m = nm;
    }
    if (hi == 0) {
      const int row = rb * 256 + wid * 32 + ns * 16 + r15;
      partial[row * NCHUNK + ch] = m + log2f(l);
    }
  }
}

// ---- kernel 3: per-row combine of chunk partials + diagonal --------------
__global__ __launch_bounds__(256) void vmse_combine(
    const float* __restrict__ partial, const float* __restrict__ diag,
    const float* __restrict__ gnorm, const float* __restrict__ sigma,
    float* __restrict__ bsum)
{
  const int r = blockIdx.x * 256 + threadIdx.x;
  const float nv = sigma[0] * sigma[0];
  float p[NCHUNK];
  float M = -3.0e38f;
  #pragma unroll
  for (int c = 0; c < NCHUNK; ++c) { p[c] = partial[r * NCHUNK + c]; M = fmaxf(M, p[c]); }
  float ssum = 0.f;
  #pragma unroll
  for (int c = 0; c < NCHUNK; ++c) ssum += exp2f(p[c] - M);
  const float lse2 = M + log2f(ssum);          // base-2 LSE of z*log2e
  const float zii = (diag[r] - 0.5f * gnorm[r]) / nv;
  float contrib = LN2F * lse2 - zii;           // lse_e - z_ii
  #pragma unroll
  for (int off = 1; off < 64; off <<= 1) contrib += __shfl_xor(contrib, off);
  __shared__ float wsum[4];
  if ((threadIdx.x & 63) == 0) wsum[threadIdx.x >> 6] = contrib;
  __syncthreads();
  if (threadIdx.x == 0)
    bsum[blockIdx.x] = (wsum[0] + wsum[1]) + (wsum[2] + wsum[3]);
}

// ---- kernel 4: deterministic finalize ------------------------------------
__global__ __launch_bounds__(64) void vmse_final(
    const float* __restrict__ bsum, const float* __restrict__ sigma,
    float* __restrict__ out)
{
  const int lane = threadIdx.x;
  float v = (lane < 32) ? bsum[lane] : 0.f;
  #pragma unroll
  for (int off = 1; off < 64; off <<= 1) v += __shfl_xor(v, off);
  if (lane == 0) {
    const float nv = sigma[0] * sigma[0];
    out[0] = v * (2.0f * nv / (float)NB);
  }
}

extern "C" void kernel_launch(void* const* d_in, const int* in_sizes, int n_in,
                              void* d_out, int out_size, void* d_ws, size_t ws_size,
                              hipStream_t stream)
{
  const float* pred  = (const float*)d_in[0];
  const float* gt    = (const float*)d_in[1];
  const float* sigma = (const float*)d_in[2];
  char* ws = (char*)d_ws;
  // ws layout: Ah 4MB | Bh 4MB | gnorm 32KB | diag 32KB | ghs 32KB | partial 512KB | bsum
  unsigned short* Ah = (unsigned short*)(ws);
  unsigned short* Bh = (unsigned short*)(ws + (4u << 20));
  float* gnorm   = (float*)(ws + (8u << 20));
  float* diag    = (float*)(ws + (8u << 20) + (32u << 10));
  float* ghs     = (float*)(ws + (8u << 20) + (64u << 10));
  float* partial = (float*)(ws + (8u << 20) + (96u << 10));
  float* bsum    = (float*)(ws + (8u << 20) + (608u << 10));

  vmse_prep<<<NB / 4, 256, 0, stream>>>(pred, gt, sigma, Ah, Bh, diag, gnorm, ghs);
  vmse_main<<<32 * NCHUNK, 512, 0, stream>>>(Ah, Bh, ghs, partial);
  vmse_combine<<<NB / 256, 256, 0, stream>>>(partial, diag, gnorm, sigma, bsum);
  vmse_final<<<1, 64, 0, stream>>>(bsum, sigma, (float*)d_out);
}